// Round 4
// baseline (499.808 us; speedup 1.0000x reference)
//
#include <hip/hip_runtime.h>
#include <math.h>

// Problem constants (from reference setup_inputs)
#define BB    8
#define DIN   1024
#define TT    2048
#define DCB   64
#define VV    8192
#define NN    (BB * TT)      // 16384 rows
#define EPSN  1e-12f

#define NCHUNK 16
#define CPC    (VV / NCHUNK) // 512 codes per chunk
#define TCODES 64            // codes per LDS tile
#define NTILE  (CPC / TCODES)

typedef float f32x4 __attribute__((ext_vector_type(4)));

// ---------------------------------------------------------------------------
// Kernel 1: normalize codebook rows -> cn, and cn2 = sum(cn*cn) per row.
// ---------------------------------------------------------------------------
__global__ void __launch_bounds__(256) k_prep_cb(const float* __restrict__ cb,
                                                 float* __restrict__ cn,
                                                 float* __restrict__ cn2) {
    int v    = blockIdx.x * 4 + (threadIdx.x >> 6);
    int k    = threadIdx.x & 63;
    float x  = cb[v * DCB + k];
    float s  = x * x;
    #pragma unroll
    for (int off = 32; off; off >>= 1) s += __shfl_xor(s, off, 64);
    float nrm = sqrtf(s);
    float den = fmaxf(nrm, EPSN);
    float c   = x / den;
    cn[v * DCB + k] = c;
    float s2 = c * c;
    #pragma unroll
    for (int off = 32; off; off >>= 1) s2 += __shfl_xor(s2, off, 64);
    if (k == 0) cn2[v] = s2;
}

// ---------------------------------------------------------------------------
// Kernel 2: transpose W [DCB, DIN] -> wt [DIN, DCB]
// ---------------------------------------------------------------------------
__global__ void __launch_bounds__(256) k_prep_wt(const float* __restrict__ W,
                                                 float* __restrict__ wt) {
    int i = blockIdx.x * 256 + threadIdx.x;
    int d = i >> 10;
    int c = i & 1023;
    wt[c * DCB + d] = W[d * DIN + c];
}

// ---------------------------------------------------------------------------
// Kernel 3: z_e = W z + b, then L2-normalize each row; store en and en2.
// row = lane (coalesced z reads), d-octet = wave (W/bias scalarized).
// ---------------------------------------------------------------------------
__global__ void __launch_bounds__(512) k_gemm_norm(const float* __restrict__ z,
                                                   const float* __restrict__ wt,
                                                   const float* __restrict__ bias,
                                                   float* __restrict__ en,
                                                   float* __restrict__ en2) {
    __shared__ float red[64][9];

    int r   = threadIdx.x & 63;
    int oct = threadIdx.x >> 6;
    int n   = blockIdx.x * 64 + r;
    int b   = n >> 11;
    int t   = n & 2047;
    int d0  = oct * 8;

    const float* zp = z + (size_t)b * (DIN * TT) + t;

    float acc[8];
    #pragma unroll
    for (int j = 0; j < 8; ++j) acc[j] = 0.0f;

    #pragma unroll 4
    for (int c = 0; c < DIN; ++c) {
        float zv = zp[(size_t)c * TT];
        const float4* w4 = (const float4*)(wt + c * DCB + d0);
        float4 w0 = w4[0];
        float4 w1 = w4[1];
        acc[0] = fmaf(zv, w0.x, acc[0]);
        acc[1] = fmaf(zv, w0.y, acc[1]);
        acc[2] = fmaf(zv, w0.z, acc[2]);
        acc[3] = fmaf(zv, w0.w, acc[3]);
        acc[4] = fmaf(zv, w1.x, acc[4]);
        acc[5] = fmaf(zv, w1.y, acc[5]);
        acc[6] = fmaf(zv, w1.z, acc[6]);
        acc[7] = fmaf(zv, w1.w, acc[7]);
    }

    float ze[8];
    #pragma unroll
    for (int j = 0; j < 8; ++j) ze[j] = acc[j] + bias[d0 + j];

    float ss = 0.0f;
    #pragma unroll
    for (int j = 0; j < 8; ++j) ss = fmaf(ze[j], ze[j], ss);
    red[r][oct] = ss;
    __syncthreads();
    float tot = 0.0f;
    #pragma unroll
    for (int j = 0; j < 8; ++j) tot += red[r][j];
    float den = fmaxf(sqrtf(tot), EPSN);

    float e[8];
    #pragma unroll
    for (int j = 0; j < 8; ++j) e[j] = ze[j] / den;

    float s2 = 0.0f;
    #pragma unroll
    for (int j = 0; j < 8; ++j) s2 = fmaf(e[j], e[j], s2);
    __syncthreads();
    red[r][oct] = s2;
    __syncthreads();
    float tot2 = 0.0f;
    #pragma unroll
    for (int j = 0; j < 8; ++j) tot2 += red[r][j];

    float4* ep = (float4*)(en + (size_t)n * DCB + d0);
    ep[0] = make_float4(e[0], e[1], e[2], e[3]);
    ep[1] = make_float4(e[4], e[5], e[6], e[7]);
    if (oct == 0) en2[n] = tot2;
}

// ---------------------------------------------------------------------------
// Kernel 4: distances + per-chunk argmax.
// en row PINNED in VGPRs via asm register barrier (defeats load remat).
// Codebook staged through double-buffered LDS, read as uniform broadcast
// ds_read_b128 (in-order lgkmcnt -> pipelinable; no SMEM in the hot loop).
// ---------------------------------------------------------------------------
__global__ void __launch_bounds__(256) k_dist(const float* __restrict__ en,
                                              const float* __restrict__ en2g,
                                              const float* __restrict__ cn,
                                              const float* __restrict__ cn2,
                                              float* __restrict__ pscore,
                                              int* __restrict__ pidx) {
    __shared__ f32x4 cbuf[2][TCODES * 16];  // 2 x 16 KB
    __shared__ float c2buf[2][TCODES];

    int tid   = threadIdx.x;
    int n     = blockIdx.x * 256 + tid;
    int chunk = blockIdx.y;
    int v0    = chunk * CPC;

    // ---- en row into 16 pinned f32x4 (64 VGPRs) ----
    const f32x4* ep = (const f32x4*)(en + (size_t)n * DCB);
    f32x4 E0 = ep[0],  E1 = ep[1],  E2 = ep[2],  E3 = ep[3];
    f32x4 E4 = ep[4],  E5 = ep[5],  E6 = ep[6],  E7 = ep[7];
    f32x4 E8 = ep[8],  E9 = ep[9],  E10 = ep[10], E11 = ep[11];
    f32x4 E12 = ep[12], E13 = ep[13], E14 = ep[14], E15 = ep[15];
    asm volatile("" : "+v"(E0), "+v"(E1), "+v"(E2), "+v"(E3),
                      "+v"(E4), "+v"(E5), "+v"(E6), "+v"(E7),
                      "+v"(E8), "+v"(E9), "+v"(E10), "+v"(E11),
                      "+v"(E12), "+v"(E13), "+v"(E14), "+v"(E15));
    float den2 = en2g[n];

    const f32x4* csrc = (const f32x4*)(cn + (size_t)v0 * DCB); // NTILE*1024 f32x4

    // stage tile 0
    {
        f32x4 r0 = csrc[tid], r1 = csrc[tid + 256],
              r2 = csrc[tid + 512], r3 = csrc[tid + 768];
        cbuf[0][tid] = r0; cbuf[0][tid + 256] = r1;
        cbuf[0][tid + 512] = r2; cbuf[0][tid + 768] = r3;
        if (tid < TCODES) c2buf[0][tid] = cn2[v0 + tid];
    }
    __syncthreads();

    float best = -INFINITY;
    int   bidx = 0;

    for (int t = 0; t < NTILE; ++t) {
        int cur = t & 1, nxt = cur ^ 1;
        f32x4 r0, r1, r2, r3;
        float rc2 = 0.0f;
        bool pf = (t + 1 < NTILE);
        if (pf) {  // issue next-tile loads early; latency hides under compute
            const f32x4* s = csrc + (size_t)(t + 1) * (TCODES * 16);
            r0 = s[tid]; r1 = s[tid + 256]; r2 = s[tid + 512]; r3 = s[tid + 768];
            if (tid < TCODES) rc2 = cn2[v0 + (t + 1) * TCODES + tid];
        }

        const f32x4* cb0 = &cbuf[cur][0];
        const float* c20 = &c2buf[cur][0];
        for (int c = 0; c < TCODES; ++c) {
            const f32x4* cp = cb0 + c * 16;  // uniform -> broadcast ds_read_b128
            float a0 = 0.0f, a1 = 0.0f, a2 = 0.0f, a3 = 0.0f;
            #define VQ_STEP(E, i)                  \
                { f32x4 cv = cp[i];                \
                  a0 = fmaf(E.x, cv.x, a0);        \
                  a1 = fmaf(E.y, cv.y, a1);        \
                  a2 = fmaf(E.z, cv.z, a2);        \
                  a3 = fmaf(E.w, cv.w, a3); }
            VQ_STEP(E0, 0)   VQ_STEP(E1, 1)   VQ_STEP(E2, 2)   VQ_STEP(E3, 3)
            VQ_STEP(E4, 4)   VQ_STEP(E5, 5)   VQ_STEP(E6, 6)   VQ_STEP(E7, 7)
            VQ_STEP(E8, 8)   VQ_STEP(E9, 9)   VQ_STEP(E10, 10) VQ_STEP(E11, 11)
            VQ_STEP(E12, 12) VQ_STEP(E13, 13) VQ_STEP(E14, 14) VQ_STEP(E15, 15)
            #undef VQ_STEP
            float dot  = (a0 + a1) + (a2 + a3);
            float dist = fmaf(-2.0f, dot, den2) + c20[c];  // same math as passing run
            float nd   = -dist;
            int v      = v0 + t * TCODES + c;
            if (nd > best) { best = nd; bidx = v; }
        }

        if (pf) {
            __syncthreads();  // everyone done reading buf[nxt] from iter t-1
            cbuf[nxt][tid] = r0; cbuf[nxt][tid + 256] = r1;
            cbuf[nxt][tid + 512] = r2; cbuf[nxt][tid + 768] = r3;
            if (tid < TCODES) c2buf[nxt][tid] = rc2;
            __syncthreads();  // writes visible before iter t+1 reads
        }
    }

    pscore[(size_t)chunk * NN + n] = best;
    pidx  [(size_t)chunk * NN + n] = bidx;
}

// ---------------------------------------------------------------------------
// Kernel 5: combine per-chunk winners (ascending chunk order preserves
// first-index tie-break). Output dtype is int32.
// ---------------------------------------------------------------------------
__global__ void __launch_bounds__(256) k_reduce(const float* __restrict__ pscore,
                                                const int* __restrict__ pidx,
                                                int* __restrict__ out) {
    int n = blockIdx.x * 256 + threadIdx.x;
    float best = -INFINITY;
    int   bi   = 0;
    #pragma unroll
    for (int c = 0; c < NCHUNK; ++c) {
        float s = pscore[(size_t)c * NN + n];
        int  id = pidx [(size_t)c * NN + n];
        if (s > best) { best = s; bi = id; }
    }
    out[n] = bi;
}

// ---------------------------------------------------------------------------
extern "C" void kernel_launch(void* const* d_in, const int* in_sizes, int n_in,
                              void* d_out, int out_size, void* d_ws, size_t ws_size,
                              hipStream_t stream) {
    const float* z  = (const float*)d_in[0];  // [8,1024,2048]
    const float* W  = (const float*)d_in[1];  // [64,1024]
    const float* bi = (const float*)d_in[2];  // [64]
    const float* cb = (const float*)d_in[3];  // [8192,64]
    int* out = (int*)d_out;                   // [16384] indices, int32

    char* ws = (char*)d_ws;
    float* cn     = (float*)(ws);                                   // 2 MB
    float* cn2    = (float*)(ws + 2097152);                         // 32 KB
    float* wt     = (float*)(ws + 2097152 + 32768);                 // 256 KB
    float* en     = (float*)(ws + 2097152 + 32768 + 262144);        // 4 MB
    float* en2    = (float*)(ws + 2097152 + 32768 + 262144 + 4194304);        // 64 KB
    float* pscore = (float*)(ws + 2097152 + 32768 + 262144 + 4194304 + 65536);// 1 MB
    int*   pidx   = (int*)  (ws + 2097152 + 32768 + 262144 + 4194304 + 65536 + 1048576); // 1 MB

    hipLaunchKernelGGL(k_prep_cb,   dim3(VV / 4),          dim3(256), 0, stream, cb, cn, cn2);
    hipLaunchKernelGGL(k_prep_wt,   dim3(DIN * DCB / 256), dim3(256), 0, stream, W, wt);
    hipLaunchKernelGGL(k_gemm_norm, dim3(NN / 64),         dim3(512), 0, stream, z, wt, bi, en, en2);
    hipLaunchKernelGGL(k_dist,      dim3(NN / 256, NCHUNK), dim3(256), 0, stream,
                       en, en2, cn, cn2, pscore, pidx);
    hipLaunchKernelGGL(k_reduce,    dim3(NN / 256),        dim3(256), 0, stream, pscore, pidx, out);
}

// Round 5
// 488.628 us; speedup vs baseline: 1.0229x; 1.0229x over previous
//
#include <hip/hip_runtime.h>
#include <math.h>

// Problem constants (from reference setup_inputs)
#define BB    8
#define DIN   1024
#define TT    2048
#define DCB   64
#define VV    8192
#define NN    (BB * TT)      // 16384 rows
#define EPSN  1e-12f

#define NCHUNK 16
#define CPC    (VV / NCHUNK) // 512 codes per chunk
#define TCODES 32            // codes per LDS tile (8 KB/tile)
#define NTILE  (CPC / TCODES)

typedef float f32x4 __attribute__((ext_vector_type(4)));

typedef const __attribute__((address_space(1))) void* gas_ptr;
typedef __attribute__((address_space(3))) void* las_ptr;

// ---------------------------------------------------------------------------
// Kernel 1: normalize codebook rows -> cn, and cn2 = sum(cn*cn) per row.
// ---------------------------------------------------------------------------
__global__ void __launch_bounds__(256) k_prep_cb(const float* __restrict__ cb,
                                                 float* __restrict__ cn,
                                                 float* __restrict__ cn2) {
    int v    = blockIdx.x * 4 + (threadIdx.x >> 6);
    int k    = threadIdx.x & 63;
    float x  = cb[v * DCB + k];
    float s  = x * x;
    #pragma unroll
    for (int off = 32; off; off >>= 1) s += __shfl_xor(s, off, 64);
    float nrm = sqrtf(s);
    float den = fmaxf(nrm, EPSN);
    float c   = x / den;
    cn[v * DCB + k] = c;
    float s2 = c * c;
    #pragma unroll
    for (int off = 32; off; off >>= 1) s2 += __shfl_xor(s2, off, 64);
    if (k == 0) cn2[v] = s2;
}

// ---------------------------------------------------------------------------
// Kernel 2: transpose W [DCB, DIN] -> wt [DIN, DCB]
// ---------------------------------------------------------------------------
__global__ void __launch_bounds__(256) k_prep_wt(const float* __restrict__ W,
                                                 float* __restrict__ wt) {
    int i = blockIdx.x * 256 + threadIdx.x;
    int d = i >> 10;
    int c = i & 1023;
    wt[c * DCB + d] = W[d * DIN + c];
}

// ---------------------------------------------------------------------------
// Kernel 3: z_e = W z + b, then L2-normalize each row; store en and en2.
// row = lane (coalesced z reads), d-octet = wave (W/bias scalarized).
// ---------------------------------------------------------------------------
__global__ void __launch_bounds__(512) k_gemm_norm(const float* __restrict__ z,
                                                   const float* __restrict__ wt,
                                                   const float* __restrict__ bias,
                                                   float* __restrict__ en,
                                                   float* __restrict__ en2) {
    __shared__ float red[64][9];

    int r   = threadIdx.x & 63;
    int oct = threadIdx.x >> 6;
    int n   = blockIdx.x * 64 + r;
    int b   = n >> 11;
    int t   = n & 2047;
    int d0  = oct * 8;

    const float* zp = z + (size_t)b * (DIN * TT) + t;

    float acc[8];
    #pragma unroll
    for (int j = 0; j < 8; ++j) acc[j] = 0.0f;

    #pragma unroll 4
    for (int c = 0; c < DIN; ++c) {
        float zv = zp[(size_t)c * TT];
        const float4* w4 = (const float4*)(wt + c * DCB + d0);
        float4 w0 = w4[0];
        float4 w1 = w4[1];
        acc[0] = fmaf(zv, w0.x, acc[0]);
        acc[1] = fmaf(zv, w0.y, acc[1]);
        acc[2] = fmaf(zv, w0.z, acc[2]);
        acc[3] = fmaf(zv, w0.w, acc[3]);
        acc[4] = fmaf(zv, w1.x, acc[4]);
        acc[5] = fmaf(zv, w1.y, acc[5]);
        acc[6] = fmaf(zv, w1.z, acc[6]);
        acc[7] = fmaf(zv, w1.w, acc[7]);
    }

    float ze[8];
    #pragma unroll
    for (int j = 0; j < 8; ++j) ze[j] = acc[j] + bias[d0 + j];

    float ss = 0.0f;
    #pragma unroll
    for (int j = 0; j < 8; ++j) ss = fmaf(ze[j], ze[j], ss);
    red[r][oct] = ss;
    __syncthreads();
    float tot = 0.0f;
    #pragma unroll
    for (int j = 0; j < 8; ++j) tot += red[r][j];
    float den = fmaxf(sqrtf(tot), EPSN);

    float e[8];
    #pragma unroll
    for (int j = 0; j < 8; ++j) e[j] = ze[j] / den;

    float s2 = 0.0f;
    #pragma unroll
    for (int j = 0; j < 8; ++j) s2 = fmaf(e[j], e[j], s2);
    __syncthreads();
    red[r][oct] = s2;
    __syncthreads();
    float tot2 = 0.0f;
    #pragma unroll
    for (int j = 0; j < 8; ++j) tot2 += red[r][j];

    float4* ep = (float4*)(en + (size_t)n * DCB + d0);
    ep[0] = make_float4(e[0], e[1], e[2], e[3]);
    ep[1] = make_float4(e[4], e[5], e[6], e[7]);
    if (oct == 0) en2[n] = tot2;
}

// ---------------------------------------------------------------------------
// Kernel 4: distances + per-chunk argmax.
// en row pinned in VGPRs (asm barrier). Codebook tiles staged global->LDS
// via __builtin_amdgcn_global_load_lds (no VGPR round-trip -> prefetch can't
// be sunk under register pressure). Double-buffered, vmcnt(0)+barrier per
// tile. cn2 slice staged once per block. Hot loop: broadcast ds_read_b128.
// ---------------------------------------------------------------------------
__global__ void __launch_bounds__(256) k_dist(const float* __restrict__ en,
                                              const float* __restrict__ en2g,
                                              const float* __restrict__ cn,
                                              const float* __restrict__ cn2,
                                              float* __restrict__ pscore,
                                              int* __restrict__ pidx) {
    __shared__ float cbuf[2][TCODES * DCB];  // 2 x 8 KB
    __shared__ float c2all[CPC];             // 2 KB, whole chunk

    int tid   = threadIdx.x;
    int w     = tid >> 6;
    int lane  = tid & 63;
    int n     = blockIdx.x * 256 + tid;
    int chunk = blockIdx.y;
    int v0    = chunk * CPC;

    const float* csrc = cn + (size_t)v0 * DCB;   // chunk's codebook rows

    // ---- stage cn2 slice for the whole chunk (once) ----
    c2all[tid]       = cn2[v0 + tid];
    c2all[tid + 256] = cn2[v0 + tid + 256];

    // ---- stage tile 0 via global_load_lds (8 x 1KB wave-calls) ----
    {
        const float* s0 = csrc;                  // tile 0
        #pragma unroll
        for (int j = 0; j < 2; ++j) {
            int call = w * 2 + j;
            const float* gs = s0 + call * 256 + lane * 4;
            float* ld = &cbuf[0][call * 256];
            __builtin_amdgcn_global_load_lds((gas_ptr)gs, (las_ptr)ld, 16, 0, 0);
        }
    }

    // ---- en row into 16 pinned f32x4 (64 VGPRs) ----
    const f32x4* ep = (const f32x4*)(en + (size_t)n * DCB);
    f32x4 E0 = ep[0],  E1 = ep[1],  E2 = ep[2],  E3 = ep[3];
    f32x4 E4 = ep[4],  E5 = ep[5],  E6 = ep[6],  E7 = ep[7];
    f32x4 E8 = ep[8],  E9 = ep[9],  E10 = ep[10], E11 = ep[11];
    f32x4 E12 = ep[12], E13 = ep[13], E14 = ep[14], E15 = ep[15];
    asm volatile("" : "+v"(E0), "+v"(E1), "+v"(E2), "+v"(E3),
                      "+v"(E4), "+v"(E5), "+v"(E6), "+v"(E7),
                      "+v"(E8), "+v"(E9), "+v"(E10), "+v"(E11),
                      "+v"(E12), "+v"(E13), "+v"(E14), "+v"(E15));
    float den2 = en2g[n];

    asm volatile("s_waitcnt vmcnt(0)" ::: "memory");
    __syncthreads();

    float best = -INFINITY;
    int   bidx = 0;

    for (int t = 0; t < NTILE; ++t) {
        int cur = t & 1, nxt = cur ^ 1;

        if (t + 1 < NTILE) {  // issue next tile's loads; latency hides under compute
            const float* s = csrc + (size_t)(t + 1) * (TCODES * DCB);
            #pragma unroll
            for (int j = 0; j < 2; ++j) {
                int call = w * 2 + j;
                const float* gs = s + call * 256 + lane * 4;
                float* ld = &cbuf[nxt][call * 256];
                __builtin_amdgcn_global_load_lds((gas_ptr)gs, (las_ptr)ld, 16, 0, 0);
            }
        }

        const f32x4* cb0 = (const f32x4*)&cbuf[cur][0];
        const float* c20 = &c2all[t * TCODES];
        #pragma unroll 2
        for (int c = 0; c < TCODES; ++c) {
            const f32x4* cp = cb0 + c * 16;  // uniform -> broadcast ds_read_b128
            float a0 = 0.0f, a1 = 0.0f, a2 = 0.0f, a3 = 0.0f;
            #define VQ_STEP(E, i)                  \
                { f32x4 cv = cp[i];                \
                  a0 = fmaf(E.x, cv.x, a0);        \
                  a1 = fmaf(E.y, cv.y, a1);        \
                  a2 = fmaf(E.z, cv.z, a2);        \
                  a3 = fmaf(E.w, cv.w, a3); }
            VQ_STEP(E0, 0)   VQ_STEP(E1, 1)   VQ_STEP(E2, 2)   VQ_STEP(E3, 3)
            VQ_STEP(E4, 4)   VQ_STEP(E5, 5)   VQ_STEP(E6, 6)   VQ_STEP(E7, 7)
            VQ_STEP(E8, 8)   VQ_STEP(E9, 9)   VQ_STEP(E10, 10) VQ_STEP(E11, 11)
            VQ_STEP(E12, 12) VQ_STEP(E13, 13) VQ_STEP(E14, 14) VQ_STEP(E15, 15)
            #undef VQ_STEP
            float dot  = (a0 + a1) + (a2 + a3);
            float dist = fmaf(-2.0f, dot, den2) + c20[c];  // same math as passing run
            float nd   = -dist;
            int v      = v0 + t * TCODES + c;
            if (nd > best) { best = nd; bidx = v; }
        }

        // next tile's LDS writes done + everyone finished reading cbuf[cur]
        asm volatile("s_waitcnt vmcnt(0)" ::: "memory");
        __syncthreads();
    }

    pscore[(size_t)chunk * NN + n] = best;
    pidx  [(size_t)chunk * NN + n] = bidx;
}

// ---------------------------------------------------------------------------
// Kernel 5: combine per-chunk winners (ascending chunk order preserves
// first-index tie-break). Output dtype is int32.
// ---------------------------------------------------------------------------
__global__ void __launch_bounds__(256) k_reduce(const float* __restrict__ pscore,
                                                const int* __restrict__ pidx,
                                                int* __restrict__ out) {
    int n = blockIdx.x * 256 + threadIdx.x;
    float best = -INFINITY;
    int   bi   = 0;
    #pragma unroll
    for (int c = 0; c < NCHUNK; ++c) {
        float s = pscore[(size_t)c * NN + n];
        int  id = pidx [(size_t)c * NN + n];
        if (s > best) { best = s; bi = id; }
    }
    out[n] = bi;
}

// ---------------------------------------------------------------------------
extern "C" void kernel_launch(void* const* d_in, const int* in_sizes, int n_in,
                              void* d_out, int out_size, void* d_ws, size_t ws_size,
                              hipStream_t stream) {
    const float* z  = (const float*)d_in[0];  // [8,1024,2048]
    const float* W  = (const float*)d_in[1];  // [64,1024]
    const float* bi = (const float*)d_in[2];  // [64]
    const float* cb = (const float*)d_in[3];  // [8192,64]
    int* out = (int*)d_out;                   // [16384] indices, int32

    char* ws = (char*)d_ws;
    float* cn     = (float*)(ws);                                   // 2 MB
    float* cn2    = (float*)(ws + 2097152);                         // 32 KB
    float* wt     = (float*)(ws + 2097152 + 32768);                 // 256 KB
    float* en     = (float*)(ws + 2097152 + 32768 + 262144);        // 4 MB
    float* en2    = (float*)(ws + 2097152 + 32768 + 262144 + 4194304);        // 64 KB
    float* pscore = (float*)(ws + 2097152 + 32768 + 262144 + 4194304 + 65536);// 1 MB
    int*   pidx   = (int*)  (ws + 2097152 + 32768 + 262144 + 4194304 + 65536 + 1048576); // 1 MB

    hipLaunchKernelGGL(k_prep_cb,   dim3(VV / 4),          dim3(256), 0, stream, cb, cn, cn2);
    hipLaunchKernelGGL(k_prep_wt,   dim3(DIN * DCB / 256), dim3(256), 0, stream, W, wt);
    hipLaunchKernelGGL(k_gemm_norm, dim3(NN / 64),         dim3(512), 0, stream, z, wt, bi, en, en2);
    hipLaunchKernelGGL(k_dist,      dim3(NN / 256, NCHUNK), dim3(256), 0, stream,
                       en, en2, cn, cn2, pscore, pidx);
    hipLaunchKernelGGL(k_reduce,    dim3(NN / 256),        dim3(256), 0, stream, pscore, pidx, out);
}

// Round 6
// 233.606 us; speedup vs baseline: 2.1395x; 2.0917x over previous
//
#include <hip/hip_runtime.h>
#include <math.h>

// Problem constants (from reference setup_inputs)
#define BB    8
#define DIN   1024
#define TT    2048
#define DCB   64
#define VV    8192
#define NN    (BB * TT)      // 16384 rows
#define EPSN  1e-12f

#define DSPLIT 2
#define CPCHUNK (VV / DSPLIT)    // 4096 codes per chunk
#define TSTEPS  (CPCHUNK / 32)   // 128 tiles of 32 codes

typedef float f32x4  __attribute__((ext_vector_type(4)));
typedef float f32x16 __attribute__((ext_vector_type(16)));
typedef int   i32x16 __attribute__((ext_vector_type(16)));
typedef _Float16 half8 __attribute__((ext_vector_type(8)));

typedef const __attribute__((address_space(1))) void* gas_ptr;
typedef __attribute__((address_space(3))) void* las_ptr;

// ---------------------------------------------------------------------------
// Kernel 1: normalize codebook rows; emit split-f16 ch (hi), cl (2048*lo),
// and c2 = sum(cn*cn) per row (f32, mirrors reference cn2).
// ---------------------------------------------------------------------------
__global__ void __launch_bounds__(256) k_prep_cb(const float* __restrict__ cb,
                                                 _Float16* __restrict__ ch,
                                                 _Float16* __restrict__ cl,
                                                 float* __restrict__ c2) {
    int v    = blockIdx.x * 4 + (threadIdx.x >> 6);
    int k    = threadIdx.x & 63;
    float x  = cb[v * DCB + k];
    float s  = x * x;
    #pragma unroll
    for (int off = 32; off; off >>= 1) s += __shfl_xor(s, off, 64);
    float den = fmaxf(sqrtf(s), EPSN);
    float c   = x / den;

    _Float16 h = (_Float16)c;
    float r    = c - (float)h;
    ch[v * DCB + k] = h;
    cl[v * DCB + k] = (_Float16)(r * 2048.0f);

    float s2 = c * c;
    #pragma unroll
    for (int off = 32; off; off >>= 1) s2 += __shfl_xor(s2, off, 64);
    if (k == 0) c2[v] = s2;
}

// ---------------------------------------------------------------------------
// Kernel 2: transpose W [DCB, DIN] -> wt [DIN, DCB]
// ---------------------------------------------------------------------------
__global__ void __launch_bounds__(256) k_prep_wt(const float* __restrict__ W,
                                                 float* __restrict__ wt) {
    int i = blockIdx.x * 256 + threadIdx.x;
    int d = i >> 10;
    int c = i & 1023;
    wt[c * DCB + d] = W[d * DIN + c];
}

// ---------------------------------------------------------------------------
// Kernel 3: z_e = W z + b, L2-normalize rows, emit split-f16 eh / el(2048x).
// row = lane (coalesced z reads), d-octet = wave (W/bias scalarized).
// ---------------------------------------------------------------------------
__global__ void __launch_bounds__(512) k_gemm_norm(const float* __restrict__ z,
                                                   const float* __restrict__ wt,
                                                   const float* __restrict__ bias,
                                                   _Float16* __restrict__ eh,
                                                   _Float16* __restrict__ el) {
    __shared__ float red[64][9];

    int r   = threadIdx.x & 63;
    int oct = threadIdx.x >> 6;
    int n   = blockIdx.x * 64 + r;
    int b   = n >> 11;
    int t   = n & 2047;
    int d0  = oct * 8;

    const float* zp = z + (size_t)b * (DIN * TT) + t;

    float acc[8];
    #pragma unroll
    for (int j = 0; j < 8; ++j) acc[j] = 0.0f;

    #pragma unroll 4
    for (int c = 0; c < DIN; ++c) {
        float zv = zp[(size_t)c * TT];
        const float4* w4 = (const float4*)(wt + c * DCB + d0);
        float4 w0 = w4[0];
        float4 w1 = w4[1];
        acc[0] = fmaf(zv, w0.x, acc[0]);
        acc[1] = fmaf(zv, w0.y, acc[1]);
        acc[2] = fmaf(zv, w0.z, acc[2]);
        acc[3] = fmaf(zv, w0.w, acc[3]);
        acc[4] = fmaf(zv, w1.x, acc[4]);
        acc[5] = fmaf(zv, w1.y, acc[5]);
        acc[6] = fmaf(zv, w1.z, acc[6]);
        acc[7] = fmaf(zv, w1.w, acc[7]);
    }

    float ze[8];
    #pragma unroll
    for (int j = 0; j < 8; ++j) ze[j] = acc[j] + bias[d0 + j];

    float ss = 0.0f;
    #pragma unroll
    for (int j = 0; j < 8; ++j) ss = fmaf(ze[j], ze[j], ss);
    red[r][oct] = ss;
    __syncthreads();
    float tot = 0.0f;
    #pragma unroll
    for (int j = 0; j < 8; ++j) tot += red[r][j];
    float den = fmaxf(sqrtf(tot), EPSN);

    half8 vh, vl;
    #pragma unroll
    for (int j = 0; j < 8; ++j) {
        float x = ze[j] / den;
        _Float16 h = (_Float16)x;
        float rr = x - (float)h;
        vh[j] = h;
        vl[j] = (_Float16)(rr * 2048.0f);
    }
    *(half8*)&eh[(size_t)n * DCB + d0] = vh;
    *(half8*)&el[(size_t)n * DCB + d0] = vl;
}

// ---------------------------------------------------------------------------
// Kernel 4: fused split-f16 MFMA GEMM + argmax.
// Block = 4 waves x 32 rows = 128 rows; blockIdx.y = code chunk (4096 codes).
// Per 32-code tile: ch/cl staged global->LDS (swizzled source, linear dest),
// frags via swizzled ds_read_b128; 12 x mfma_f32_32x32x16_f16
// (hh: 4, mid = eh*cl_s + el_s*ch: 8). score = 2*(hh + mid/2048) - c2.
// C layout (guide-verified): col=lane&31 (code), row=(i&3)+8*(i>>2)+4*(lane>>5).
// ---------------------------------------------------------------------------
__global__ void __launch_bounds__(256) k_distmax(const _Float16* __restrict__ eh,
                                                 const _Float16* __restrict__ el,
                                                 const _Float16* __restrict__ chg,
                                                 const _Float16* __restrict__ clg,
                                                 const float* __restrict__ c2,
                                                 float* __restrict__ pscore,
                                                 int* __restrict__ pidx) {
    __shared__ __align__(1024) char smem[2][2][4096];  // [buf][h/l][4KB tile]

    int tid  = threadIdx.x;
    int w    = tid >> 6;
    int lane = tid & 63;
    int rr   = lane & 31;   // A: row slot / B: code slot / C: col
    int hhf  = lane >> 5;   // k-half selector
    int chunk = blockIdx.y;
    int v0   = chunk * CPCHUNK;
    int m0   = blockIdx.x * 128 + w * 32;

    // ---- A-frags: en row (m0+rr), split hi/lo, 4 K-chunks each ----
    const char* ehp = (const char*)(eh + (size_t)(m0 + rr) * DCB) + hhf * 16;
    const char* elp = (const char*)(el + (size_t)(m0 + rr) * DCB) + hhf * 16;
    half8 ah0 = *(const half8*)(ehp +  0), ah1 = *(const half8*)(ehp + 32);
    half8 ah2 = *(const half8*)(ehp + 64), ah3 = *(const half8*)(ehp + 96);
    half8 al0 = *(const half8*)(elp +  0), al1 = *(const half8*)(elp + 32);
    half8 al2 = *(const half8*)(elp + 64), al3 = *(const half8*)(elp + 96);
    asm volatile("" : "+v"(ah0), "+v"(ah1), "+v"(ah2), "+v"(ah3),
                      "+v"(al0), "+v"(al1), "+v"(al2), "+v"(al3));

    // ---- staging: swizzled global source -> linear LDS dest ----
    #define STAGE(b, t)                                                          \
    {                                                                            \
        const char* chs = (const char*)chg + ((size_t)(v0 + (t) * 32)) * 128;    \
        const char* cls = (const char*)clg + ((size_t)(v0 + (t) * 32)) * 128;    \
        _Pragma("unroll")                                                        \
        for (int j = 0; j < 2; ++j) {                                            \
            int cc   = w * 2 + j;                                                \
            int part = cc & 3;                                                   \
            int lin  = part * 1024 + (lane << 4);                                \
            int so   = lin ^ (((lin >> 7) & 7) << 4);                            \
            const char* gs = (cc < 4 ? chs : cls) + so;                          \
            __builtin_amdgcn_global_load_lds((gas_ptr)gs,                        \
                (las_ptr)&smem[b][cc >= 4][part * 1024], 16, 0, 0);              \
        }                                                                        \
    }

    STAGE(0, 0);

    f32x16 kz;
    f32x16 best;
    i32x16 bidx;
    #pragma unroll
    for (int i = 0; i < 16; ++i) { kz[i] = 0.0f; best[i] = -INFINITY; bidx[i] = 0; }

    asm volatile("s_waitcnt vmcnt(0)" ::: "memory");
    __syncthreads();

    int lin0 = rr * 128 + hhf * 16;  // frag byte base within tile

    for (int t = 0; t < TSTEPS; ++t) {
        int cur = t & 1;
        if (t + 1 < TSTEPS) STAGE(cur ^ 1, t + 1);

        int   vcode = v0 + t * 32 + rr;
        float c2v   = c2[vcode];

        #define SWZ(x) ((x) ^ ((((x) >> 7) & 7) << 4))
        half8 bh0 = *(const half8*)&smem[cur][0][SWZ(lin0 +  0)];
        half8 bh1 = *(const half8*)&smem[cur][0][SWZ(lin0 + 32)];
        half8 bh2 = *(const half8*)&smem[cur][0][SWZ(lin0 + 64)];
        half8 bh3 = *(const half8*)&smem[cur][0][SWZ(lin0 + 96)];
        half8 bl0 = *(const half8*)&smem[cur][1][SWZ(lin0 +  0)];
        half8 bl1 = *(const half8*)&smem[cur][1][SWZ(lin0 + 32)];
        half8 bl2 = *(const half8*)&smem[cur][1][SWZ(lin0 + 64)];
        half8 bl3 = *(const half8*)&smem[cur][1][SWZ(lin0 + 96)];
        #undef SWZ

        f32x16 Ahh, Amid;
        Ahh  = __builtin_amdgcn_mfma_f32_32x32x16_f16(ah0, bh0, kz, 0, 0, 0);
        Amid = __builtin_amdgcn_mfma_f32_32x32x16_f16(ah0, bl0, kz, 0, 0, 0);
        Amid = __builtin_amdgcn_mfma_f32_32x32x16_f16(al0, bh0, Amid, 0, 0, 0);
        Ahh  = __builtin_amdgcn_mfma_f32_32x32x16_f16(ah1, bh1, Ahh, 0, 0, 0);
        Amid = __builtin_amdgcn_mfma_f32_32x32x16_f16(ah1, bl1, Amid, 0, 0, 0);
        Amid = __builtin_amdgcn_mfma_f32_32x32x16_f16(al1, bh1, Amid, 0, 0, 0);
        Ahh  = __builtin_amdgcn_mfma_f32_32x32x16_f16(ah2, bh2, Ahh, 0, 0, 0);
        Amid = __builtin_amdgcn_mfma_f32_32x32x16_f16(ah2, bl2, Amid, 0, 0, 0);
        Amid = __builtin_amdgcn_mfma_f32_32x32x16_f16(al2, bh2, Amid, 0, 0, 0);
        Ahh  = __builtin_amdgcn_mfma_f32_32x32x16_f16(ah3, bh3, Ahh, 0, 0, 0);
        Amid = __builtin_amdgcn_mfma_f32_32x32x16_f16(ah3, bl3, Amid, 0, 0, 0);
        Amid = __builtin_amdgcn_mfma_f32_32x32x16_f16(al3, bh3, Amid, 0, 0, 0);

        #pragma unroll
        for (int i = 0; i < 16; ++i) {
            float dot = fmaf(Amid[i], 4.8828125e-4f, Ahh[i]);  // hh + mid/2048
            float s   = fmaf(2.0f, dot, -c2v);                 // 2*dot - cn2
            bool  g   = s > best[i];
            best[i]   = g ? s : best[i];
            bidx[i]   = g ? vcode : bidx[i];
        }

        asm volatile("s_waitcnt vmcnt(0)" ::: "memory");
        __syncthreads();
    }
    #undef STAGE

    // ---- cross-lane argmax per output row (32 lanes share a row-set) ----
    #pragma unroll
    for (int i = 0; i < 16; ++i) {
        float bv = best[i];
        int   bi = bidx[i];
        #pragma unroll
        for (int off = 1; off < 32; off <<= 1) {
            float ob = __shfl_xor(bv, off, 64);
            int   oi = __shfl_xor(bi, off, 64);
            if (ob > bv || (ob == bv && oi < bi)) { bv = ob; bi = oi; }
        }
        if (rr == 0) {
            int row = m0 + (i & 3) + 8 * (i >> 2) + 4 * hhf;
            pscore[(size_t)chunk * NN + row] = bv;
            pidx  [(size_t)chunk * NN + row] = bi;
        }
    }
}

// ---------------------------------------------------------------------------
// Kernel 5: combine per-chunk winners (ascending chunk order preserves
// first-index tie-break). Output dtype is int32.
// ---------------------------------------------------------------------------
__global__ void __launch_bounds__(256) k_reduce(const float* __restrict__ pscore,
                                                const int* __restrict__ pidx,
                                                int* __restrict__ out) {
    int n = blockIdx.x * 256 + threadIdx.x;
    float best = -INFINITY;
    int   bi   = 0;
    #pragma unroll
    for (int c = 0; c < DSPLIT; ++c) {
        float s = pscore[(size_t)c * NN + n];
        int  id = pidx [(size_t)c * NN + n];
        if (s > best) { best = s; bi = id; }
    }
    out[n] = bi;
}

// ---------------------------------------------------------------------------
extern "C" void kernel_launch(void* const* d_in, const int* in_sizes, int n_in,
                              void* d_out, int out_size, void* d_ws, size_t ws_size,
                              hipStream_t stream) {
    const float* z  = (const float*)d_in[0];  // [8,1024,2048]
    const float* W  = (const float*)d_in[1];  // [64,1024]
    const float* bi = (const float*)d_in[2];  // [64]
    const float* cb = (const float*)d_in[3];  // [8192,64]
    int* out = (int*)d_out;                   // [16384] indices, int32

    char* ws = (char*)d_ws;
    _Float16* ch  = (_Float16*)(ws);                         // 1 MB
    _Float16* cl  = (_Float16*)(ws + 1048576);               // 1 MB
    float*    c2  = (float*)   (ws + 2097152);               // 32 KB
    float*    wt  = (float*)   (ws + 2129920);               // 256 KB
    _Float16* eh  = (_Float16*)(ws + 2392064);               // 2 MB
    _Float16* el  = (_Float16*)(ws + 4489216);               // 2 MB
    float* pscore = (float*)   (ws + 6586368);               // 128 KB
    int*   pidx   = (int*)     (ws + 6717440);               // 128 KB

    hipLaunchKernelGGL(k_prep_cb,   dim3(VV / 4),          dim3(256), 0, stream, cb, ch, cl, c2);
    hipLaunchKernelGGL(k_prep_wt,   dim3(DIN * DCB / 256), dim3(256), 0, stream, W, wt);
    hipLaunchKernelGGL(k_gemm_norm, dim3(NN / 64),         dim3(512), 0, stream, z, wt, bi, eh, el);
    hipLaunchKernelGGL(k_distmax,   dim3(NN / 128, DSPLIT), dim3(256), 0, stream,
                       eh, el, ch, cl, c2, pscore, pidx);
    hipLaunchKernelGGL(k_reduce,    dim3(NN / 256),        dim3(256), 0, stream, pscore, pidx, out);
}

// Round 7
// 149.258 us; speedup vs baseline: 3.3486x; 1.5651x over previous
//
#include <hip/hip_runtime.h>
#include <math.h>

// Problem constants (from reference setup_inputs)
#define BB    8
#define DIN   1024
#define TT    2048
#define DCB   64
#define VV    8192
#define NN    (BB * TT)      // 16384 rows
#define EPSN  1e-12f

#define KSPLIT 4
#define KCH    (DIN / KSPLIT)    // 256 c's per k-chunk

#define DSPLIT 4
#define CPCHUNK (VV / DSPLIT)    // 2048 codes per chunk
#define TSTEPS  (CPCHUNK / 32)   // 64 tiles of 32 codes

typedef float f32x4  __attribute__((ext_vector_type(4)));
typedef float f32x16 __attribute__((ext_vector_type(16)));
typedef int   i32x16 __attribute__((ext_vector_type(16)));
typedef _Float16 half8 __attribute__((ext_vector_type(8)));

typedef const __attribute__((address_space(1))) void* gas_ptr;
typedef __attribute__((address_space(3))) void* las_ptr;

// ---------------------------------------------------------------------------
// Kernel 1: normalize codebook rows; emit split-f16 ch (hi), cl (2048*lo),
// and c2 = sum(cn*cn) per row (f32, mirrors reference cn2).
// ---------------------------------------------------------------------------
__global__ void __launch_bounds__(256) k_prep_cb(const float* __restrict__ cb,
                                                 _Float16* __restrict__ ch,
                                                 _Float16* __restrict__ cl,
                                                 float* __restrict__ c2) {
    int v    = blockIdx.x * 4 + (threadIdx.x >> 6);
    int k    = threadIdx.x & 63;
    float x  = cb[v * DCB + k];
    float s  = x * x;
    #pragma unroll
    for (int off = 32; off; off >>= 1) s += __shfl_xor(s, off, 64);
    float den = fmaxf(sqrtf(s), EPSN);
    float c   = x / den;

    _Float16 h = (_Float16)c;
    float r    = c - (float)h;
    ch[v * DCB + k] = h;
    cl[v * DCB + k] = (_Float16)(r * 2048.0f);

    float s2 = c * c;
    #pragma unroll
    for (int off = 32; off; off >>= 1) s2 += __shfl_xor(s2, off, 64);
    if (k == 0) c2[v] = s2;
}

// ---------------------------------------------------------------------------
// Kernel 2: transpose W [DCB, DIN] -> wt [DIN, DCB]
// ---------------------------------------------------------------------------
__global__ void __launch_bounds__(256) k_prep_wt(const float* __restrict__ W,
                                                 float* __restrict__ wt) {
    int i = blockIdx.x * 256 + threadIdx.x;
    int d = i >> 10;
    int c = i & 1023;
    wt[c * DCB + d] = W[d * DIN + c];
}

// ---------------------------------------------------------------------------
// Kernel 3a: partial projection GEMM, K-split by 4.
// Thread: 4 consecutive t (float4 z loads) x 8 d = 32 accs.
// Block 256 threads: lanes 0-31 cover 128 consecutive t (512B/wave-instr),
// oct = tid>>5 picks the d-octet. Grid (128 row-blocks, 4 k-chunks).
// ---------------------------------------------------------------------------
__global__ void __launch_bounds__(256) k_gemm_part(const float* __restrict__ z,
                                                   const float* __restrict__ wt,
                                                   float* __restrict__ part) {
    int tid = threadIdx.x;
    int tg  = tid & 31;          // t-group within block
    int oct = tid >> 5;          // 0..7
    int d0  = oct * 8;
    int n0  = blockIdx.x * 128;  // 128 rows per block (single batch: 2048%128==0)
    int ks  = blockIdx.y;
    int c0  = ks * KCH;
    int b   = n0 >> 11;
    int t0  = (n0 & 2047) + tg * 4;

    const float* zp = z + (size_t)b * (DIN * TT) + (size_t)c0 * TT + t0;

    float acc0[8], acc1[8], acc2[8], acc3[8];
    #pragma unroll
    for (int j = 0; j < 8; ++j) { acc0[j] = 0.f; acc1[j] = 0.f; acc2[j] = 0.f; acc3[j] = 0.f; }

    #pragma unroll 4
    for (int c = 0; c < KCH; ++c) {
        float4 zv = *(const float4*)(zp + (size_t)c * TT);
        const float4* w4 = (const float4*)(wt + (size_t)(c0 + c) * DCB + d0);
        float4 w0 = w4[0], w1 = w4[1];
        float wj[8] = {w0.x, w0.y, w0.z, w0.w, w1.x, w1.y, w1.z, w1.w};
        #pragma unroll
        for (int j = 0; j < 8; ++j) {
            acc0[j] = fmaf(zv.x, wj[j], acc0[j]);
            acc1[j] = fmaf(zv.y, wj[j], acc1[j]);
            acc2[j] = fmaf(zv.z, wj[j], acc2[j]);
            acc3[j] = fmaf(zv.w, wj[j], acc3[j]);
        }
    }

    float* pp = part + ((size_t)ks * NN + (n0 + tg * 4)) * DCB + d0;
    *(float4*)(pp + 0 * DCB)     = make_float4(acc0[0], acc0[1], acc0[2], acc0[3]);
    *(float4*)(pp + 0 * DCB + 4) = make_float4(acc0[4], acc0[5], acc0[6], acc0[7]);
    *(float4*)(pp + 1 * DCB)     = make_float4(acc1[0], acc1[1], acc1[2], acc1[3]);
    *(float4*)(pp + 1 * DCB + 4) = make_float4(acc1[4], acc1[5], acc1[6], acc1[7]);
    *(float4*)(pp + 2 * DCB)     = make_float4(acc2[0], acc2[1], acc2[2], acc2[3]);
    *(float4*)(pp + 2 * DCB + 4) = make_float4(acc2[4], acc2[5], acc2[6], acc2[7]);
    *(float4*)(pp + 3 * DCB)     = make_float4(acc3[0], acc3[1], acc3[2], acc3[3]);
    *(float4*)(pp + 3 * DCB + 4) = make_float4(acc3[4], acc3[5], acc3[6], acc3[7]);
}

// ---------------------------------------------------------------------------
// Kernel 3b: combine partials + bias, L2-normalize rows, emit split-f16.
// 8 consecutive lanes share a row (shfl-xor 1/2/4 row reduction).
// ---------------------------------------------------------------------------
__global__ void __launch_bounds__(256) k_combine(const float* __restrict__ part,
                                                 const float* __restrict__ bias,
                                                 _Float16* __restrict__ eh,
                                                 _Float16* __restrict__ el) {
    int gid = blockIdx.x * 256 + threadIdx.x;  // 0..131071
    int n   = gid >> 3;
    int d0  = (gid & 7) * 8;

    float ze[8];
    #pragma unroll
    for (int j = 0; j < 8; ++j) ze[j] = bias[d0 + j];

    #pragma unroll
    for (int ks = 0; ks < KSPLIT; ++ks) {
        const float4* pp = (const float4*)(part + ((size_t)ks * NN + n) * DCB + d0);
        float4 p0 = pp[0], p1 = pp[1];
        ze[0] += p0.x; ze[1] += p0.y; ze[2] += p0.z; ze[3] += p0.w;
        ze[4] += p1.x; ze[5] += p1.y; ze[6] += p1.z; ze[7] += p1.w;
    }

    float ss = 0.0f;
    #pragma unroll
    for (int j = 0; j < 8; ++j) ss = fmaf(ze[j], ze[j], ss);
    ss += __shfl_xor(ss, 1, 64);
    ss += __shfl_xor(ss, 2, 64);
    ss += __shfl_xor(ss, 4, 64);
    float den = fmaxf(sqrtf(ss), EPSN);

    half8 vh, vl;
    #pragma unroll
    for (int j = 0; j < 8; ++j) {
        float x = ze[j] / den;
        _Float16 h = (_Float16)x;
        vh[j] = h;
        vl[j] = (_Float16)((x - (float)h) * 2048.0f);
    }
    *(half8*)&eh[(size_t)n * DCB + d0] = vh;
    *(half8*)&el[(size_t)n * DCB + d0] = vl;
}

// ---------------------------------------------------------------------------
// Kernel 4: fused split-f16 MFMA GEMM + argmax (unchanged structure, DSPLIT=4).
// ---------------------------------------------------------------------------
__global__ void __launch_bounds__(256) k_distmax(const _Float16* __restrict__ eh,
                                                 const _Float16* __restrict__ el,
                                                 const _Float16* __restrict__ chg,
                                                 const _Float16* __restrict__ clg,
                                                 const float* __restrict__ c2,
                                                 float* __restrict__ pscore,
                                                 int* __restrict__ pidx) {
    __shared__ __align__(1024) char smem[2][2][4096];  // [buf][h/l][4KB tile]

    int tid  = threadIdx.x;
    int w    = tid >> 6;
    int lane = tid & 63;
    int rr   = lane & 31;   // A: row slot / B: code slot / C: col
    int hhf  = lane >> 5;   // k-half selector
    int chunk = blockIdx.y;
    int v0   = chunk * CPCHUNK;
    int m0   = blockIdx.x * 128 + w * 32;

    // ---- A-frags: en row (m0+rr), split hi/lo, 4 K-chunks each ----
    const char* ehp = (const char*)(eh + (size_t)(m0 + rr) * DCB) + hhf * 16;
    const char* elp = (const char*)(el + (size_t)(m0 + rr) * DCB) + hhf * 16;
    half8 ah0 = *(const half8*)(ehp +  0), ah1 = *(const half8*)(ehp + 32);
    half8 ah2 = *(const half8*)(ehp + 64), ah3 = *(const half8*)(ehp + 96);
    half8 al0 = *(const half8*)(elp +  0), al1 = *(const half8*)(elp + 32);
    half8 al2 = *(const half8*)(elp + 64), al3 = *(const half8*)(elp + 96);
    asm volatile("" : "+v"(ah0), "+v"(ah1), "+v"(ah2), "+v"(ah3),
                      "+v"(al0), "+v"(al1), "+v"(al2), "+v"(al3));

    // ---- staging: swizzled global source -> linear LDS dest ----
    #define STAGE(b, t)                                                          \
    {                                                                            \
        const char* chs = (const char*)chg + ((size_t)(v0 + (t) * 32)) * 128;    \
        const char* cls = (const char*)clg + ((size_t)(v0 + (t) * 32)) * 128;    \
        _Pragma("unroll")                                                        \
        for (int j = 0; j < 2; ++j) {                                            \
            int cc   = w * 2 + j;                                                \
            int part = cc & 3;                                                   \
            int lin  = part * 1024 + (lane << 4);                                \
            int so   = lin ^ (((lin >> 7) & 7) << 4);                            \
            const char* gs = (cc < 4 ? chs : cls) + so;                          \
            __builtin_amdgcn_global_load_lds((gas_ptr)gs,                        \
                (las_ptr)&smem[b][cc >= 4][part * 1024], 16, 0, 0);              \
        }                                                                        \
    }

    STAGE(0, 0);

    f32x16 kz;
    f32x16 best;
    i32x16 bidx;
    #pragma unroll
    for (int i = 0; i < 16; ++i) { kz[i] = 0.0f; best[i] = -INFINITY; bidx[i] = 0; }

    asm volatile("s_waitcnt vmcnt(0)" ::: "memory");
    __syncthreads();

    int lin0 = rr * 128 + hhf * 16;  // frag byte base within tile

    for (int t = 0; t < TSTEPS; ++t) {
        int cur = t & 1;
        if (t + 1 < TSTEPS) STAGE(cur ^ 1, t + 1);

        int   vcode = v0 + t * 32 + rr;
        float c2v   = c2[vcode];

        #define SWZ(x) ((x) ^ ((((x) >> 7) & 7) << 4))
        half8 bh0 = *(const half8*)&smem[cur][0][SWZ(lin0 +  0)];
        half8 bh1 = *(const half8*)&smem[cur][0][SWZ(lin0 + 32)];
        half8 bh2 = *(const half8*)&smem[cur][0][SWZ(lin0 + 64)];
        half8 bh3 = *(const half8*)&smem[cur][0][SWZ(lin0 + 96)];
        half8 bl0 = *(const half8*)&smem[cur][1][SWZ(lin0 +  0)];
        half8 bl1 = *(const half8*)&smem[cur][1][SWZ(lin0 + 32)];
        half8 bl2 = *(const half8*)&smem[cur][1][SWZ(lin0 + 64)];
        half8 bl3 = *(const half8*)&smem[cur][1][SWZ(lin0 + 96)];
        #undef SWZ

        f32x16 Ahh, Amid;
        Ahh  = __builtin_amdgcn_mfma_f32_32x32x16_f16(ah0, bh0, kz, 0, 0, 0);
        Amid = __builtin_amdgcn_mfma_f32_32x32x16_f16(ah0, bl0, kz, 0, 0, 0);
        Amid = __builtin_amdgcn_mfma_f32_32x32x16_f16(al0, bh0, Amid, 0, 0, 0);
        Ahh  = __builtin_amdgcn_mfma_f32_32x32x16_f16(ah1, bh1, Ahh, 0, 0, 0);
        Amid = __builtin_amdgcn_mfma_f32_32x32x16_f16(ah1, bl1, Amid, 0, 0, 0);
        Amid = __builtin_amdgcn_mfma_f32_32x32x16_f16(al1, bh1, Amid, 0, 0, 0);
        Ahh  = __builtin_amdgcn_mfma_f32_32x32x16_f16(ah2, bh2, Ahh, 0, 0, 0);
        Amid = __builtin_amdgcn_mfma_f32_32x32x16_f16(ah2, bl2, Amid, 0, 0, 0);
        Amid = __builtin_amdgcn_mfma_f32_32x32x16_f16(al2, bh2, Amid, 0, 0, 0);
        Ahh  = __builtin_amdgcn_mfma_f32_32x32x16_f16(ah3, bh3, Ahh, 0, 0, 0);
        Amid = __builtin_amdgcn_mfma_f32_32x32x16_f16(ah3, bl3, Amid, 0, 0, 0);
        Amid = __builtin_amdgcn_mfma_f32_32x32x16_f16(al3, bh3, Amid, 0, 0, 0);

        #pragma unroll
        for (int i = 0; i < 16; ++i) {
            float dot = fmaf(Amid[i], 4.8828125e-4f, Ahh[i]);  // hh + mid/2048
            float s   = fmaf(2.0f, dot, -c2v);                 // 2*dot - cn2
            bool  g   = s > best[i];
            best[i]   = g ? s : best[i];
            bidx[i]   = g ? vcode : bidx[i];
        }

        asm volatile("s_waitcnt vmcnt(0)" ::: "memory");
        __syncthreads();
    }
    #undef STAGE

    // ---- cross-lane argmax per output row (32 lanes share a row-set) ----
    #pragma unroll
    for (int i = 0; i < 16; ++i) {
        float bv = best[i];
        int   bi = bidx[i];
        #pragma unroll
        for (int off = 1; off < 32; off <<= 1) {
            float ob = __shfl_xor(bv, off, 64);
            int   oi = __shfl_xor(bi, off, 64);
            if (ob > bv || (ob == bv && oi < bi)) { bv = ob; bi = oi; }
        }
        if (rr == 0) {
            int row = m0 + (i & 3) + 8 * (i >> 2) + 4 * hhf;
            pscore[(size_t)chunk * NN + row] = bv;
            pidx  [(size_t)chunk * NN + row] = bi;
        }
    }
}

// ---------------------------------------------------------------------------
// Kernel 5: combine per-chunk winners (ascending chunk order preserves
// first-index tie-break). Output dtype is int32.
// ---------------------------------------------------------------------------
__global__ void __launch_bounds__(256) k_reduce(const float* __restrict__ pscore,
                                                const int* __restrict__ pidx,
                                                int* __restrict__ out) {
    int n = blockIdx.x * 256 + threadIdx.x;
    float best = -INFINITY;
    int   bi   = 0;
    #pragma unroll
    for (int c = 0; c < DSPLIT; ++c) {
        float s = pscore[(size_t)c * NN + n];
        int  id = pidx [(size_t)c * NN + n];
        if (s > best) { best = s; bi = id; }
    }
    out[n] = bi;
}

// ---------------------------------------------------------------------------
extern "C" void kernel_launch(void* const* d_in, const int* in_sizes, int n_in,
                              void* d_out, int out_size, void* d_ws, size_t ws_size,
                              hipStream_t stream) {
    const float* z  = (const float*)d_in[0];  // [8,1024,2048]
    const float* W  = (const float*)d_in[1];  // [64,1024]
    const float* bi = (const float*)d_in[2];  // [64]
    const float* cb = (const float*)d_in[3];  // [8192,64]
    int* out = (int*)d_out;                   // [16384] indices, int32

    char* ws = (char*)d_ws;
    _Float16* ch  = (_Float16*)(ws);                         // 1 MB
    _Float16* cl  = (_Float16*)(ws + 1048576);               // 1 MB
    float*    c2  = (float*)   (ws + 2097152);               // 32 KB
    float*    wt  = (float*)   (ws + 2129920);               // 256 KB
    _Float16* eh  = (_Float16*)(ws + 2392064);               // 2 MB
    _Float16* el  = (_Float16*)(ws + 4489216);               // 2 MB
    float* pscore = (float*)   (ws + 6586368);               // 256 KB
    int*   pidx   = (int*)     (ws + 6848512);               // 256 KB
    float* part   = (float*)   (ws + 7110656);               // 16 MB

    hipLaunchKernelGGL(k_prep_cb,   dim3(VV / 4),          dim3(256), 0, stream, cb, ch, cl, c2);
    hipLaunchKernelGGL(k_prep_wt,   dim3(DIN * DCB / 256), dim3(256), 0, stream, W, wt);
    hipLaunchKernelGGL(k_gemm_part, dim3(NN / 128, KSPLIT), dim3(256), 0, stream, z, wt, part);
    hipLaunchKernelGGL(k_combine,   dim3(NN * 8 / 256),    dim3(256), 0, stream, part, bi, eh, el);
    hipLaunchKernelGGL(k_distmax,   dim3(NN / 128, DSPLIT), dim3(256), 0, stream,
                       eh, el, ch, cl, c2, pscore, pidx);
    hipLaunchKernelGGL(k_reduce,    dim3(NN / 256),        dim3(256), 0, stream, pscore, pidx, out);
}